// Round 11
// baseline (155.404 us; speedup 1.0000x reference)
//
#include <hip/hip_runtime.h>
#include <hip/hip_bf16.h>
#include <math.h>

typedef __attribute__((ext_vector_type(8))) short short8;  // 8 bf16 = 4 VGPRs
typedef __attribute__((ext_vector_type(4))) float f32x4;
// 4B-aligned float4: CDNA global loads support dword-aligned dwordx4.
typedef float f32x4u __attribute__((vector_size(16), aligned(4)));

// Problem dims
#define D0n 8
#define D1n 12
#define D2n 6
#define Ln 2000
#define An 21
#define KPn 8
#define Un 48
#define PPn 1993              // L - k + 1
#define Bn 576                // D0*D1*D2
#define S_SIZE 4608           // (D0*D1) * U
#define R_SIZE 8064
#define RB_BYTES (384 * 64)   // 8q * 48u rows of 64B (bf16, padded, swizzled)

// XOR swizzle within each 512B (8-row) group; bijective, 16B-granular.
__device__ __forceinline__ int swz(int b) { return b ^ ((b >> 2) & 0x70); }

__device__ __forceinline__ unsigned int fkey(float f) {
    unsigned int u = __float_as_uint(f);
    return (u & 0x80000000u) ? ~u : (u | 0x80000000u);
}
__device__ __forceinline__ float funkey(unsigned int k) {
    return __uint_as_float((k & 0x80000000u) ? (k ^ 0x80000000u) : ~k);
}
__device__ __forceinline__ unsigned short f2bf(float v) {
    unsigned int b = __float_as_uint(v);
    return (unsigned short)((b + 0x7FFFu + ((b >> 16) & 1u)) >> 16);  // RNE
}
// Pack two floats -> one dword of 2 bf16 (compiler fuses to v_cvt_pk_bf16_f32)
__device__ __forceinline__ unsigned int pk2(float lo, float hi) {
    __hip_bfloat16 a = __float2bfloat16(lo);
    __hip_bfloat16 b = __float2bfloat16(hi);
    return (unsigned int)__bfloat16_as_ushort(a) |
           ((unsigned int)__bfloat16_as_ushort(b) << 16);
}

#define GLOAD_LDS16(g, l)                                                     \
    __builtin_amdgcn_global_load_lds(                                          \
        (const __attribute__((address_space(1))) void*)(g),                    \
        (__attribute__((address_space(3))) void*)(l), 16, 0, 0)

// Kernel 1: zero S-keys; R = log(max(softmax(P_logit)/Q, eps)) -> fp32 to
// d_out + bf16 padded(21->32, pad cols ZERO - this is what makes unmasked
// X over-reads safe) pre-swizzled copy to ws.
__global__ void k_profile(const float* __restrict__ P_logit,
                          const float* __restrict__ Q,
                          float* __restrict__ Rout,
                          unsigned short* __restrict__ Rb,
                          unsigned int* __restrict__ Skey) {
    int t = blockIdx.x * blockDim.x + threadIdx.x;
    if (t < S_SIZE) Skey[t] = 0u;
    if (t >= KPn * Un) return;
    int kp = t / Un, u = t % Un;
    const float* pl = P_logit + kp * (An * Un) + u;
    float v[An];
    float m = -INFINITY;
#pragma unroll
    for (int a = 0; a < An; ++a) { v[a] = pl[a * Un]; m = fmaxf(m, v[a]); }
    float s = 0.f;
#pragma unroll
    for (int a = 0; a < An; ++a) { v[a] = expf(v[a] - m); s += v[a]; }
    float inv = 1.f / s;
    int rowp = kp * Un + u;
#pragma unroll
    for (int a = 0; a < An; ++a) {
        float r = logf(fmaxf(v[a] * inv / Q[a], 1e-6f));
        Rout[(kp * An + a) * Un + u] = r;
        Rb[swz(rowp * 64 + a * 2) >> 1] = f2bf(r);
    }
#pragma unroll
    for (int a = An; a < 32; ++a) Rb[swz(rowp * 64 + a * 2) >> 1] = 0;
}

// One 64-position x 48-u wave tile. X read DIRECTLY from global (L2-hot),
// converted fp32->bf16 in-register. R from LDS (swizzled). No barriers.
// SAFE: clamp rows + restricted loads (only the p0w==1984 tile can run past
// the X allocation; clamped-row garbage only feeds masked p >= PPn).
template <bool SAFE>
__device__ __forceinline__ void do_tile(const float* __restrict__ Xb,
                                        const char* __restrict__ rbase,
                                        int p0w, int lr, int ls,
                                        float* __restrict__ Zb,
                                        float smax[3][4]) {
    f32x4 acc[3][4];
#pragma unroll
    for (int nu = 0; nu < 3; ++nu)
#pragma unroll
        for (int f = 0; f < 4; ++f) acc[nu][f] = (f32x4){0.f, 0.f, 0.f, 0.f};

#pragma unroll 2
    for (int q = 0; q < KPn; ++q) {
        short8 xf[4];
#pragma unroll
        for (int f = 0; f < 4; ++f) {
            int row = p0w + f * 16 + q + lr;
            if (SAFE) row = min(row, Ln - 1);
            const float* src = Xb + (size_t)row * An + ls * 8;
            float e0, e1, e2, e3, e4, e5, e6, e7;
            if (!SAFE) {
                // ls*8 in {0,8,16,24}: elems >= 21 read the next row's finite
                // values; R pad columns are zero, so contributions vanish.
                f32x4u a = *(const f32x4u*)src;
                f32x4u b = *(const f32x4u*)(src + 4);
                e0 = a[0]; e1 = a[1]; e2 = a[2]; e3 = a[3];
                e4 = b[0]; e5 = b[1]; e6 = b[2]; e7 = b[3];
            } else {
                if (ls < 2) {
                    f32x4u a = *(const f32x4u*)src;
                    f32x4u b = *(const f32x4u*)(src + 4);
                    e0 = a[0]; e1 = a[1]; e2 = a[2]; e3 = a[3];
                    e4 = b[0]; e5 = b[1]; e6 = b[2]; e7 = b[3];
                } else if (ls == 2) {  // elems 16-20 only (no overshoot)
                    f32x4u a = *(const f32x4u*)src;
                    e0 = a[0]; e1 = a[1]; e2 = a[2]; e3 = a[3];
                    e4 = src[4]; e5 = 0.f; e6 = 0.f; e7 = 0.f;
                } else {               // pure pad octet
                    e0 = e1 = e2 = e3 = e4 = e5 = e6 = e7 = 0.f;
                }
            }
            union { unsigned int w[4]; short8 s; } u;
            u.w[0] = pk2(e0, e1); u.w[1] = pk2(e2, e3);
            u.w[2] = pk2(e4, e5); u.w[3] = pk2(e6, e7);
            xf[f] = u.s;
        }
        const int rr = q * Un + lr;
        short8 rf0 = *(const short8*)(rbase + swz(rr * 64 + ls * 16));
        short8 rf1 = *(const short8*)(rbase + swz((rr + 16) * 64 + ls * 16));
        short8 rf2 = *(const short8*)(rbase + swz((rr + 32) * 64 + ls * 16));
#pragma unroll
        for (int f = 0; f < 4; ++f) {
            acc[0][f] = __builtin_amdgcn_mfma_f32_16x16x32_bf16(rf0, xf[f], acc[0][f], 0, 0, 0);
            acc[1][f] = __builtin_amdgcn_mfma_f32_16x16x32_bf16(rf1, xf[f], acc[1][f], 0, 0, 0);
            acc[2][f] = __builtin_amdgcn_mfma_f32_16x16x32_bf16(rf2, xf[f], acc[2][f], 0, 0, 0);
        }
    }

    // Z stores: lane owns Z[p = p0w+f*16+lr][u = nu*16+ls*4 .. +3].
#pragma unroll
    for (int f = 0; f < 4; ++f) {
        int p = p0w + f * 16 + lr;
        if (p < PPn) {
            float* zp = Zb + (size_t)p * Un + ls * 4;
#pragma unroll
            for (int nu = 0; nu < 3; ++nu) {
                *(f32x4*)(zp + nu * 16) = acc[nu][f];
#pragma unroll
                for (int r = 0; r < 4; ++r)
                    smax[nu][r] = fmaxf(smax[nu][r], acc[nu][f][r]);
            }
        }
    }
}

// Kernel 2: grid (4, 576), 256 threads = 4 independent waves. One barrier
// total (R stage). Each wave: 2 rounds x 64 positions.
__global__ __launch_bounds__(256) void k_conv(
        const float* __restrict__ X,
        const unsigned short* __restrict__ Rb,
        float* __restrict__ Z,
        unsigned int* __restrict__ Skey) {
    __shared__ char rlds[RB_BYTES];
    const int b = blockIdx.y;
    const int bx = blockIdx.x;
    const int t = threadIdx.x;
    const int w = t >> 6;
    const int l = t & 63;
    const int lr = l & 15;
    const int ls = l >> 4;

    {   // Stage R once (async DMA; ws copy already bf16+padded+swizzled).
        const char* src = (const char*)Rb;
#pragma unroll
        for (int i = 0; i < RB_BYTES / 16 / 256; ++i) {  // 6
            int idx = t + i * 256;
            GLOAD_LDS16(src + idx * 16, rlds + idx * 16);
        }
    }
    __syncthreads();  // only barrier in the kernel

    const float* Xb = X + (size_t)b * Ln * An;
    float* Zb = Z + (size_t)b * PPn * Un;

    float smax[3][4];
#pragma unroll
    for (int nu = 0; nu < 3; ++nu)
#pragma unroll
        for (int r = 0; r < 4; ++r) smax[nu][r] = -INFINITY;

#pragma unroll
    for (int rnd = 0; rnd < 2; ++rnd) {
        int p0w = bx * 512 + rnd * 256 + w * 64;
        if (p0w == 1984)
            do_tile<true>(Xb, rlds, p0w, lr, ls, Zb, smax);
        else
            do_tile<false>(Xb, rlds, p0w, lr, ls, Zb, smax);
    }

    // Wave-local S reduction over positions (lr bits), then direct atomics.
#pragma unroll
    for (int nu = 0; nu < 3; ++nu)
#pragma unroll
        for (int r = 0; r < 4; ++r) {
            float v = smax[nu][r];
            v = fmaxf(v, __shfl_xor(v, 1));
            v = fmaxf(v, __shfl_xor(v, 2));
            v = fmaxf(v, __shfl_xor(v, 4));
            v = fmaxf(v, __shfl_xor(v, 8));
            smax[nu][r] = v;
        }
    if (lr == 0) {
        const int grp = b / D2n;
#pragma unroll
        for (int nu = 0; nu < 3; ++nu)
#pragma unroll
            for (int r = 0; r < 4; ++r)
                atomicMax(&Skey[grp * Un + nu * 16 + ls * 4 + r],
                          fkey(smax[nu][r]));
    }
}

// Kernel 3: decode monotone keys -> float S, in place.
__global__ void k_decode(unsigned int* __restrict__ Skey) {
    int t = blockIdx.x * blockDim.x + threadIdx.x;
    if (t < S_SIZE) {
        float f = funkey(Skey[t]);
        ((float*)Skey)[t] = f;
    }
}

extern "C" void kernel_launch(void* const* d_in, const int* in_sizes, int n_in,
                              void* d_out, int out_size, void* d_ws, size_t ws_size,
                              hipStream_t stream) {
    const float* X = (const float*)d_in[0];
    const float* P_logit = (const float*)d_in[1];
    const float* Q = (const float*)d_in[2];

    float* S = (float*)d_out;
    float* Rout = S + S_SIZE;
    float* Z = Rout + R_SIZE;
    unsigned short* Rb = (unsigned short*)d_ws;  // 24576 bytes of ws

    k_profile<<<(S_SIZE + 63) / 64, 64, 0, stream>>>(P_logit, Q, Rout, Rb,
                                                     (unsigned int*)d_out);

    dim3 grid(4, Bn);  // 4 x 512 positions = 2048 >= 1993; 2304 blocks = 9/CU
    k_conv<<<grid, 256, 0, stream>>>(X, Rb, Z, (unsigned int*)d_out);

    k_decode<<<(S_SIZE + 255) / 256, 256, 0, stream>>>((unsigned int*)d_out);
}

// Round 12
// 116.822 us; speedup vs baseline: 1.3303x; 1.3303x over previous
//
#include <hip/hip_runtime.h>
#include <hip/hip_bf16.h>
#include <math.h>

typedef __attribute__((ext_vector_type(8))) short short8;  // 8 bf16 = 4 VGPRs
typedef __attribute__((ext_vector_type(4))) float f32x4;
typedef float f32x4u __attribute__((vector_size(16), aligned(4)));
typedef unsigned int uint32_t_;

// Problem dims
#define D0n 8
#define D1n 12
#define D2n 6
#define Ln 2000
#define An 21
#define KPn 8
#define Un 48
#define PPn 1993              // L - k + 1
#define Bn 576                // D0*D1*D2
#define S_SIZE 4608           // (D0*D1) * U
#define R_SIZE 8064

// Conv tiling: one 512-position tile per block; 8 waves x 64 positions.
// grid (4, 576) = 2304 blocks = 9/CU queued, 2 resident (58KB LDS).
#define TPn 512
#define XROWS 520              // 512 + 8 halo
#define XS_BYTES (XROWS * 64)  // 33280
#define RB_BYTES (384 * 64)    // 24576
#define BOFF XS_BYTES

// XOR swizzle within each 512B (8-row) group; bijective involution on the
// byte address (bits 4-6 ^= bits 6-8), 16B-granular. Writer+reader both apply.
__device__ __forceinline__ int swz(int b) { return b ^ ((b >> 2) & 0x70); }

__device__ __forceinline__ unsigned int fkey(float f) {
    unsigned int u = __float_as_uint(f);
    return (u & 0x80000000u) ? ~u : (u | 0x80000000u);
}
__device__ __forceinline__ float funkey(unsigned int k) {
    return __uint_as_float((k & 0x80000000u) ? (k ^ 0x80000000u) : ~k);
}
__device__ __forceinline__ unsigned short f2bf(float v) {
    unsigned int b = __float_as_uint(v);
    return (unsigned short)((b + 0x7FFFu + ((b >> 16) & 1u)) >> 16);  // RNE
}
// Pack two floats -> dword of 2 bf16 (fuses to v_cvt_pk_bf16_f32).
__device__ __forceinline__ unsigned int pk2(float lo, float hi) {
    __hip_bfloat16 a = __float2bfloat16(lo);
    __hip_bfloat16 b = __float2bfloat16(hi);
    return (unsigned int)__bfloat16_as_ushort(a) |
           ((unsigned int)__bfloat16_as_ushort(b) << 16);
}

#define GLOAD_LDS16(g, l)                                                     \
    __builtin_amdgcn_global_load_lds(                                          \
        (const __attribute__((address_space(1))) void*)(g),                    \
        (__attribute__((address_space(3))) void*)(l), 16, 0, 0)

// Kernel 1: zero S-keys; R = log(max(softmax(P_logit)/Q, eps)) -> fp32 to
// d_out + bf16 padded(21->32, pad cols ZERO) pre-swizzled copy to ws.
__global__ void k_profile(const float* __restrict__ P_logit,
                          const float* __restrict__ Q,
                          float* __restrict__ Rout,
                          unsigned short* __restrict__ Rb,
                          unsigned int* __restrict__ Skey) {
    int t = blockIdx.x * blockDim.x + threadIdx.x;
    if (t < S_SIZE) Skey[t] = 0u;
    if (t >= KPn * Un) return;
    int kp = t / Un, u = t % Un;
    const float* pl = P_logit + kp * (An * Un) + u;
    float v[An];
    float m = -INFINITY;
#pragma unroll
    for (int a = 0; a < An; ++a) { v[a] = pl[a * Un]; m = fmaxf(m, v[a]); }
    float s = 0.f;
#pragma unroll
    for (int a = 0; a < An; ++a) { v[a] = expf(v[a] - m); s += v[a]; }
    float inv = 1.f / s;
    int rowp = kp * Un + u;
#pragma unroll
    for (int a = 0; a < An; ++a) {
        float r = logf(fmaxf(v[a] * inv / Q[a], 1e-6f));
        Rout[(kp * An + a) * Un + u] = r;
        Rb[swz(rowp * 64 + a * 2) >> 1] = f2bf(r);
    }
#pragma unroll
    for (int a = An; a < 32; ++a) Rb[swz(rowp * 64 + a * 2) >> 1] = 0;
}

// Kernel 2: ONE tile of 512 positions per block; ONE barrier per block.
// Stage: thread t owns row(s) {t, t+512}: 6 coalesced global loads ->
// 16 bf16 dwords in-register (pads zeroed) -> 4 ds_write_b128 (swizzled).
// Compute: wave w owns 64 positions; per q: 3 R-frags reused over 4 X-frags
// (7 ds_read_b128 / 12 MFMA). Epilogue: dwordx4 Z stores + per-wave atomics.
__global__ __launch_bounds__(512, 4) void k_conv(
        const float* __restrict__ X,
        const unsigned short* __restrict__ Rb,
        float* __restrict__ Z,
        unsigned int* __restrict__ Skey) {
    __shared__ char smem[XS_BYTES + RB_BYTES];
    const int b = blockIdx.y;
    const int base_p = blockIdx.x * TPn;
    const int t = threadIdx.x;
    const int w = t >> 6;
    const int l = t & 63;
    const int lr = l & 15;
    const int ls = l >> 4;
    const int pw = w * 64;

    {   // Stage R (async DMA; ws copy already bf16+padded+swizzled, linear).
        const char* src = (const char*)Rb;
        char* dst = smem + BOFF;
#pragma unroll
        for (int i = 0; i < RB_BYTES / 16 / 512; ++i) {  // 3
            int idx = t + i * 512;
            GLOAD_LDS16(src + idx * 16, dst + idx * 16);
        }
    }

    // Stage X: full rows per thread. Tail rows (tile 3) left unstaged: they
    // only feed p >= PPn lanes whose stores/smax are masked.
    {
        const int rows = min(XROWS, Ln - base_p);
        const float* Xb = X + (size_t)b * Ln * An;
        for (int r0 = t; r0 < XROWS; r0 += 512) {
            if (r0 < rows) {
                const float* src = Xb + (size_t)(base_p + r0) * An;
                f32x4u a0 = *(const f32x4u*)(src);
                f32x4u a1 = *(const f32x4u*)(src + 4);
                f32x4u a2 = *(const f32x4u*)(src + 8);
                f32x4u a3 = *(const f32x4u*)(src + 12);
                f32x4u a4 = *(const f32x4u*)(src + 16);
                float f20 = src[20];                 // exact end, no overread
                unsigned int dw[16];
                dw[0] = pk2(a0[0], a0[1]);  dw[1] = pk2(a0[2], a0[3]);
                dw[2] = pk2(a1[0], a1[1]);  dw[3] = pk2(a1[2], a1[3]);
                dw[4] = pk2(a2[0], a2[1]);  dw[5] = pk2(a2[2], a2[3]);
                dw[6] = pk2(a3[0], a3[1]);  dw[7] = pk2(a3[2], a3[3]);
                dw[8] = pk2(a4[0], a4[1]);  dw[9] = pk2(a4[2], a4[3]);
                dw[10] = pk2(f20, 0.f);
                dw[11] = dw[12] = dw[13] = dw[14] = dw[15] = 0u;  // pad cols
#pragma unroll
                for (int j = 0; j < 4; ++j) {
                    uint4 v = {dw[4 * j], dw[4 * j + 1],
                               dw[4 * j + 2], dw[4 * j + 3]};
                    *(uint4*)(smem + swz(r0 * 64 + j * 16)) = v;
                }
            }
        }
    }
    __syncthreads();  // the only barrier: publishes X writes + drains R DMA

    f32x4 acc[3][4];
#pragma unroll
    for (int nu = 0; nu < 3; ++nu)
#pragma unroll
        for (int f = 0; f < 4; ++f) acc[nu][f] = (f32x4){0.f, 0.f, 0.f, 0.f};

#pragma unroll
    for (int q = 0; q < KPn; ++q) {
        const int rr = q * Un + lr;
        short8 rf0 = *(const short8*)(smem + BOFF + swz(rr * 64 + ls * 16));
        short8 rf1 = *(const short8*)(smem + BOFF + swz((rr + 16) * 64 + ls * 16));
        short8 rf2 = *(const short8*)(smem + BOFF + swz((rr + 32) * 64 + ls * 16));
#pragma unroll
        for (int f = 0; f < 4; ++f) {
            const int xr = pw + f * 16 + q + lr;
            short8 xf = *(const short8*)(smem + swz(xr * 64 + ls * 16));
            acc[0][f] = __builtin_amdgcn_mfma_f32_16x16x32_bf16(rf0, xf, acc[0][f], 0, 0, 0);
            acc[1][f] = __builtin_amdgcn_mfma_f32_16x16x32_bf16(rf1, xf, acc[1][f], 0, 0, 0);
            acc[2][f] = __builtin_amdgcn_mfma_f32_16x16x32_bf16(rf2, xf, acc[2][f], 0, 0, 0);
        }
    }

    // Z stores + per-lane max. Lane owns Z[p = base+pw+f*16+lr][u = nu*16+ls*4..+3].
    float smax[3][4];
#pragma unroll
    for (int nu = 0; nu < 3; ++nu)
#pragma unroll
        for (int r = 0; r < 4; ++r) smax[nu][r] = -INFINITY;

    float* Zb = Z + (size_t)b * PPn * Un;
#pragma unroll
    for (int f = 0; f < 4; ++f) {
        int p = base_p + pw + f * 16 + lr;
        if (p < PPn) {
            float* zp = Zb + (size_t)p * Un + ls * 4;
#pragma unroll
            for (int nu = 0; nu < 3; ++nu) {
                *(f32x4*)(zp + nu * 16) = acc[nu][f];
#pragma unroll
                for (int r = 0; r < 4; ++r)
                    smax[nu][r] = fmaxf(smax[nu][r], acc[nu][f][r]);
            }
        }
    }

    // Per-wave S reduction over positions (lr bits), then direct atomics.
    const int grp = b / D2n;
#pragma unroll
    for (int nu = 0; nu < 3; ++nu)
#pragma unroll
        for (int r = 0; r < 4; ++r) {
            float v = smax[nu][r];
            v = fmaxf(v, __shfl_xor(v, 1));
            v = fmaxf(v, __shfl_xor(v, 2));
            v = fmaxf(v, __shfl_xor(v, 4));
            v = fmaxf(v, __shfl_xor(v, 8));
            if (lr == 0)
                atomicMax(&Skey[grp * Un + nu * 16 + ls * 4 + r], fkey(v));
        }
}

// Kernel 3: decode monotone keys -> float S, in place.
__global__ void k_decode(unsigned int* __restrict__ Skey) {
    int t = blockIdx.x * blockDim.x + threadIdx.x;
    if (t < S_SIZE) {
        float f = funkey(Skey[t]);
        ((float*)Skey)[t] = f;
    }
}

extern "C" void kernel_launch(void* const* d_in, const int* in_sizes, int n_in,
                              void* d_out, int out_size, void* d_ws, size_t ws_size,
                              hipStream_t stream) {
    const float* X = (const float*)d_in[0];
    const float* P_logit = (const float*)d_in[1];
    const float* Q = (const float*)d_in[2];

    float* S = (float*)d_out;
    float* Rout = S + S_SIZE;
    float* Z = Rout + R_SIZE;
    unsigned short* Rb = (unsigned short*)d_ws;  // 24576 bytes of ws

    k_profile<<<(S_SIZE + 63) / 64, 64, 0, stream>>>(P_logit, Q, Rout, Rb,
                                                     (unsigned int*)d_out);

    dim3 grid(4, Bn);  // 4 tiles x 512 positions = 2048 >= 1993
    k_conv<<<grid, 512, 0, stream>>>(X, Rb, Z, (unsigned int*)d_out);

    k_decode<<<(S_SIZE + 255) / 256, 256, 0, stream>>>((unsigned int*)d_out);
}

// Round 13
// 114.245 us; speedup vs baseline: 1.3603x; 1.0226x over previous
//
#include <hip/hip_runtime.h>
#include <hip/hip_bf16.h>
#include <math.h>

typedef __attribute__((ext_vector_type(8))) short short8;  // 8 bf16 = 4 VGPRs
typedef __attribute__((ext_vector_type(4))) float f32x4;

// Problem dims
#define D0n 8
#define D1n 12
#define D2n 6
#define Ln 2000
#define An 21
#define KPn 8
#define Un 48
#define PPn 1993              // L - k + 1
#define Bn 576                // D0*D1*D2
#define S_SIZE 4608           // (D0*D1) * U
#define R_SIZE 8064

// Conv tiling: 256 threads = 4 waves, each wave 64 positions x 48 u.
// One 256-position tile per block; grid (8,576) = 4608 blocks = 18/CU.
// LDS 41.5KB -> 3 blocks/CU resident (phase mixing); VGPR <=128 target.
#define BPn 256
#define NBX 8
#define XROWS 264              // 256 + 8 halo
#define XS_BYTES (XROWS * 64)  // 16896
#define RB_BYTES (384 * 64)    // 24576
#define BOFF XS_BYTES
#define NG 6                   // staging chunks: ceil(1386/256)

// XOR swizzle within each 512B (8-row) group; bijective involution,
// 16B-granular. Writer and reader both apply it.
__device__ __forceinline__ int swz(int b) { return b ^ ((b >> 2) & 0x70); }

__device__ __forceinline__ unsigned int fkey(float f) {
    unsigned int u = __float_as_uint(f);
    return (u & 0x80000000u) ? ~u : (u | 0x80000000u);
}
__device__ __forceinline__ float funkey(unsigned int k) {
    return __uint_as_float((k & 0x80000000u) ? (k ^ 0x80000000u) : ~k);
}
__device__ __forceinline__ unsigned short f2bf(float v) {
    unsigned int b = __float_as_uint(v);
    return (unsigned short)((b + 0x7FFFu + ((b >> 16) & 1u)) >> 16);  // RNE
}

#define GLOAD_LDS16(g, l)                                                     \
    __builtin_amdgcn_global_load_lds(                                          \
        (const __attribute__((address_space(1))) void*)(g),                    \
        (__attribute__((address_space(3))) void*)(l), 16, 0, 0)

// Kernel 1: zero S-keys; R = log(max(softmax(P_logit)/Q, eps)) -> fp32 to
// d_out + bf16 padded(21->32, pad cols ZERO — the correctness keystone that
// makes X-pad garbage harmless) pre-swizzled copy to ws.
__global__ void k_profile(const float* __restrict__ P_logit,
                          const float* __restrict__ Q,
                          float* __restrict__ Rout,
                          unsigned short* __restrict__ Rb,
                          unsigned int* __restrict__ Skey) {
    int t = blockIdx.x * blockDim.x + threadIdx.x;
    if (t < S_SIZE) Skey[t] = 0u;
    if (t >= KPn * Un) return;
    int kp = t / Un, u = t % Un;
    const float* pl = P_logit + kp * (An * Un) + u;
    float v[An];
    float m = -INFINITY;
#pragma unroll
    for (int a = 0; a < An; ++a) { v[a] = pl[a * Un]; m = fmaxf(m, v[a]); }
    float s = 0.f;
#pragma unroll
    for (int a = 0; a < An; ++a) { v[a] = expf(v[a] - m); s += v[a]; }
    float inv = 1.f / s;
    int rowp = kp * Un + u;
#pragma unroll
    for (int a = 0; a < An; ++a) {
        float r = logf(fmaxf(v[a] * inv / Q[a], 1e-6f));
        Rout[(kp * An + a) * Un + u] = r;
        Rb[swz(rowp * 64 + a * 2) >> 1] = f2bf(r);
    }
#pragma unroll
    for (int a = An; a < 32; ++a) Rb[swz(rowp * 64 + a * 2) >> 1] = 0;
}

// Scatter one flat float4 (4 consecutive X elems) into swizzled bf16 LDS.
__device__ __forceinline__ void xwrite4(char* xbase, int idx, f32x4 g) {
    int fi = idx * 4;
    int row = fi / An;          // magic-mul
    int a = fi - row * An;
#pragma unroll
    for (int e = 0; e < 4; ++e) {
        *(unsigned short*)(xbase + swz(row * 64 + a * 2)) = f2bf(g[e]);
        ++a;
        if (a == An) { a = 0; ++row; }
    }
}

// Kernel 2: single 256-pos tile, 4 waves x 64 pos, one barrier, per-wave
// atomics. Staging: coalesced flat loads + scatter LDS writes; X pad cols
// (22-31) written zero explicitly (R-pads are zero so X value is don't-care,
// but must be FINITE — stale LDS could be NaN-patterned).
__global__ __launch_bounds__(256) void k_conv(
        const float* __restrict__ X,
        const unsigned short* __restrict__ Rb,
        float* __restrict__ Z,
        unsigned int* __restrict__ Skey) {
    __shared__ char smem[XS_BYTES + RB_BYTES];
    const int b = blockIdx.y;
    const int base_p = blockIdx.x * BPn;
    const int t = threadIdx.x;
    const int l = t & 63;
    const int w = t >> 6;
    const int lr = l & 15;
    const int ls = l >> 4;
    const int pw = w * 64;

    // 1) Issue coalesced X loads (flat float4; lane-contiguous).
    const int rows = min(XROWS, Ln - base_p);
    const int n4 = rows * An / 4;   // rows in {264,208} -> *21/4 integral
    f32x4 g[NG];
    {
        const f32x4* src = (const f32x4*)(X + ((size_t)b * Ln + base_p) * An);
#pragma unroll
        for (int i = 0; i < NG; ++i) {
            int idx = t + i * 256;
            g[i] = (idx < n4) ? src[idx] : (f32x4){0.f, 0.f, 0.f, 0.f};
        }
    }
    // 2) Issue async R stage (linear DMA of pre-swizzled ws copy).
    {
        const char* src = (const char*)Rb;
        char* dst = smem + BOFF;
#pragma unroll
        for (int i = 0; i < RB_BYTES / 16 / 256; ++i) {  // 6
            int idx = t + i * 256;
            GLOAD_LDS16(src + idx * 16, dst + idx * 16);
        }
    }
    // 3) Zero the X pad columns (bytes 44..63 of each row) — independent of g.
    for (int j = t; j < XROWS * 5; j += 256) {
        int row = j / 5, pr = 11 + (j - row * 5);
        *(unsigned int*)(smem + swz(row * 64 + pr * 4)) = 0u;
    }
    // 4) Convert + scatter-write X (vmcnt waits inserted per-use).
#pragma unroll
    for (int i = 0; i < NG; ++i) {
        int idx = t + i * 256;
        if (idx < n4) xwrite4((char*)smem, idx, g[i]);
    }
    __syncthreads();  // publishes X writes + drains R DMA

    // q-loop: A = R rows (u), B = X rows (positions). Per q: 3 R-frags
    // reused over 4 X-frags -> 7 ds_read_b128 / 12 MFMA.
    f32x4 acc[3][4];
#pragma unroll
    for (int nu = 0; nu < 3; ++nu)
#pragma unroll
        for (int f = 0; f < 4; ++f) acc[nu][f] = (f32x4){0.f, 0.f, 0.f, 0.f};

#pragma unroll
    for (int q = 0; q < KPn; ++q) {
        const int rr = q * Un + lr;
        short8 rf0 = *(const short8*)(smem + BOFF + swz(rr * 64 + ls * 16));
        short8 rf1 = *(const short8*)(smem + BOFF + swz((rr + 16) * 64 + ls * 16));
        short8 rf2 = *(const short8*)(smem + BOFF + swz((rr + 32) * 64 + ls * 16));
#pragma unroll
        for (int f = 0; f < 4; ++f) {
            const int xr = pw + f * 16 + q + lr;
            short8 xf = *(const short8*)(smem + swz(xr * 64 + ls * 16));
            acc[0][f] = __builtin_amdgcn_mfma_f32_16x16x32_bf16(rf0, xf, acc[0][f], 0, 0, 0);
            acc[1][f] = __builtin_amdgcn_mfma_f32_16x16x32_bf16(rf1, xf, acc[1][f], 0, 0, 0);
            acc[2][f] = __builtin_amdgcn_mfma_f32_16x16x32_bf16(rf2, xf, acc[2][f], 0, 0, 0);
        }
    }

    // Z stores + per-lane max. Lane owns Z[p=base+pw+f*16+lr][u=nu*16+ls*4..+3].
    float smax[3][4];
#pragma unroll
    for (int nu = 0; nu < 3; ++nu)
#pragma unroll
        for (int r = 0; r < 4; ++r) smax[nu][r] = -INFINITY;

    float* Zb = Z + (size_t)b * PPn * Un;
#pragma unroll
    for (int f = 0; f < 4; ++f) {
        int p = base_p + pw + f * 16 + lr;
        if (p < PPn) {
            float* zp = Zb + (size_t)p * Un + ls * 4;
#pragma unroll
            for (int nu = 0; nu < 3; ++nu) {
                *(f32x4*)(zp + nu * 16) = acc[nu][f];
#pragma unroll
                for (int r = 0; r < 4; ++r)
                    smax[nu][r] = fmaxf(smax[nu][r], acc[nu][f][r]);
            }
        }
    }

    // Per-wave S reduction over the 16 position-lanes, then direct atomics.
    const int grp = b / D2n;
#pragma unroll
    for (int nu = 0; nu < 3; ++nu)
#pragma unroll
        for (int r = 0; r < 4; ++r) {
            float v = smax[nu][r];
            v = fmaxf(v, __shfl_xor(v, 1));
            v = fmaxf(v, __shfl_xor(v, 2));
            v = fmaxf(v, __shfl_xor(v, 4));
            v = fmaxf(v, __shfl_xor(v, 8));
            if (lr == 0)
                atomicMax(&Skey[grp * Un + nu * 16 + ls * 4 + r], fkey(v));
        }
}

// Kernel 3: decode monotone keys -> float S, in place.
__global__ void k_decode(unsigned int* __restrict__ Skey) {
    int t = blockIdx.x * blockDim.x + threadIdx.x;
    if (t < S_SIZE) {
        float f = funkey(Skey[t]);
        ((float*)Skey)[t] = f;
    }
}

extern "C" void kernel_launch(void* const* d_in, const int* in_sizes, int n_in,
                              void* d_out, int out_size, void* d_ws, size_t ws_size,
                              hipStream_t stream) {
    const float* X = (const float*)d_in[0];
    const float* P_logit = (const float*)d_in[1];
    const float* Q = (const float*)d_in[2];

    float* S = (float*)d_out;
    float* Rout = S + S_SIZE;
    float* Z = Rout + R_SIZE;
    unsigned short* Rb = (unsigned short*)d_ws;  // 24576 bytes of ws

    k_profile<<<(S_SIZE + 63) / 64, 64, 0, stream>>>(P_logit, Q, Rout, Rb,
                                                     (unsigned int*)d_out);

    dim3 grid(NBX, Bn);  // 8 x 256 positions = 2048 >= 1993
    k_conv<<<grid, 256, 0, stream>>>(X, Rb, Z, (unsigned int*)d_out);

    k_decode<<<(S_SIZE + 255) / 256, 256, 0, stream>>>((unsigned int*)d_out);
}

// Round 14
// 104.670 us; speedup vs baseline: 1.4847x; 1.0915x over previous
//
#include <hip/hip_runtime.h>
#include <hip/hip_bf16.h>
#include <math.h>

typedef __attribute__((ext_vector_type(8))) short short8;  // 8 bf16 = 4 VGPRs
typedef __attribute__((ext_vector_type(4))) float f32x4;

// Problem dims
#define D0n 8
#define D1n 12
#define D2n 6
#define Ln 2000
#define An 21
#define KPn 8
#define Un 48
#define PPn 1993              // L - k + 1
#define Bn 576                // D0*D1*D2
#define S_SIZE 4608           // (D0*D1) * U
#define R_SIZE 8064

// Conv tiling: 512 threads = 8 waves, each wave 64 positions x 48 u.
// ONE 512-position tile per block; grid (4,576) = 2304 blocks = 9/CU exact,
// 57.9KB LDS -> 2 resident blocks/CU = 16 waves/CU.
#define BPn 512
#define NBX 4
#define XROWS 520              // 512 + 8 halo
#define XS_BYTES (XROWS * 64)  // 33280
#define RB_BYTES (384 * 64)    // 24576
#define BOFF XS_BYTES
#define NG 6                   // staging chunks: ceil(2730/512)

// XOR swizzle within each 512B (8-row) group; bijective involution,
// 16B-granular. Writer and reader both apply it.
__device__ __forceinline__ int swz(int b) { return b ^ ((b >> 2) & 0x70); }

__device__ __forceinline__ unsigned int fkey(float f) {
    unsigned int u = __float_as_uint(f);
    return (u & 0x80000000u) ? ~u : (u | 0x80000000u);
}
__device__ __forceinline__ float funkey(unsigned int k) {
    return __uint_as_float((k & 0x80000000u) ? (k ^ 0x80000000u) : ~k);
}
__device__ __forceinline__ unsigned short f2bf(float v) {
    unsigned int b = __float_as_uint(v);
    return (unsigned short)((b + 0x7FFFu + ((b >> 16) & 1u)) >> 16);  // RNE
}

#define GLOAD_LDS16(g, l)                                                     \
    __builtin_amdgcn_global_load_lds(                                          \
        (const __attribute__((address_space(1))) void*)(g),                    \
        (__attribute__((address_space(3))) void*)(l), 16, 0, 0)

// Kernel 1: zero S-keys; R = log(max(softmax(P_logit)/Q, eps)) -> fp32 to
// d_out + bf16 padded(21->32, pad cols ZERO — keystone that makes X-pad
// garbage harmless) pre-swizzled copy to ws.
__global__ void k_profile(const float* __restrict__ P_logit,
                          const float* __restrict__ Q,
                          float* __restrict__ Rout,
                          unsigned short* __restrict__ Rb,
                          unsigned int* __restrict__ Skey) {
    int t = blockIdx.x * blockDim.x + threadIdx.x;
    if (t < S_SIZE) Skey[t] = 0u;
    if (t >= KPn * Un) return;
    int kp = t / Un, u = t % Un;
    const float* pl = P_logit + kp * (An * Un) + u;
    float v[An];
    float m = -INFINITY;
#pragma unroll
    for (int a = 0; a < An; ++a) { v[a] = pl[a * Un]; m = fmaxf(m, v[a]); }
    float s = 0.f;
#pragma unroll
    for (int a = 0; a < An; ++a) { v[a] = expf(v[a] - m); s += v[a]; }
    float inv = 1.f / s;
    int rowp = kp * Un + u;
#pragma unroll
    for (int a = 0; a < An; ++a) {
        float r = logf(fmaxf(v[a] * inv / Q[a], 1e-6f));
        Rout[(kp * An + a) * Un + u] = r;
        Rb[swz(rowp * 64 + a * 2) >> 1] = f2bf(r);
    }
#pragma unroll
    for (int a = An; a < 32; ++a) Rb[swz(rowp * 64 + a * 2) >> 1] = 0;
}

// Scatter one flat float4 (4 consecutive X elems) into swizzled bf16 LDS.
__device__ __forceinline__ void xwrite4(char* xbase, int idx, f32x4 g) {
    int fi = idx * 4;
    int row = fi / An;          // magic-mul
    int a = fi - row * An;
#pragma unroll
    for (int e = 0; e < 4; ++e) {
        *(unsigned short*)(xbase + swz(row * 64 + a * 2)) = f2bf(g[e]);
        ++a;
        if (a == An) { a = 0; ++row; }
    }
}

// Kernel 2: one 512-pos tile, 8 waves x 64 pos, ONE barrier, per-wave
// atomics, NT Z-stores. Staging: coalesced flat float4 loads + scatter LDS
// writes (the R11/R12-proven rule: global stays lane-contiguous, LDS
// absorbs the layout change).
__global__ __launch_bounds__(512) void k_conv(
        const float* __restrict__ X,
        const unsigned short* __restrict__ Rb,
        float* __restrict__ Z,
        unsigned int* __restrict__ Skey) {
    __shared__ char smem[XS_BYTES + RB_BYTES];
    const int b = blockIdx.y;
    const int base_p = blockIdx.x * BPn;
    const int t = threadIdx.x;
    const int l = t & 63;
    const int w = t >> 6;
    const int lr = l & 15;
    const int ls = l >> 4;
    const int pw = w * 64;

    // 1) Issue coalesced X loads (flat float4; lane-contiguous).
    const int rows = min(XROWS, Ln - base_p);   // 520 or 464 (bx=3)
    const int n4 = rows * An / 4;               // integral for both
    f32x4 g[NG];
    {
        const f32x4* src = (const f32x4*)(X + ((size_t)b * Ln + base_p) * An);
#pragma unroll
        for (int i = 0; i < NG; ++i) {
            int idx = t + i * 512;
            g[i] = (idx < n4) ? src[idx] : (f32x4){0.f, 0.f, 0.f, 0.f};
        }
    }
    // 2) Issue async R stage (linear DMA of pre-swizzled ws copy).
    {
        const char* src = (const char*)Rb;
        char* dst = smem + BOFF;
#pragma unroll
        for (int i = 0; i < RB_BYTES / 16 / 512; ++i) {  // 3
            int idx = t + i * 512;
            GLOAD_LDS16(src + idx * 16, dst + idx * 16);
        }
    }
    // 3) Zero X pad bytes 42..63 of every row (elements 21..31). Disjoint
    //    bytes from xwrite4's writes -> no race within the barrier interval.
    for (int row = t; row < XROWS; row += 512) {
        *(unsigned short*)(smem + swz(row * 64 + 42)) = 0;
#pragma unroll
        for (int j = 0; j < 5; ++j)
            *(unsigned int*)(smem + swz(row * 64 + 44 + 4 * j)) = 0u;
    }
    // 4) Zero tail rows (only bx=3: rows 464..519) — they feed only masked
    //    p >= PPn lanes, but must be finite.
    if (rows < XROWS) {
        uint4 z4 = {0u, 0u, 0u, 0u};
        for (int j = t; j < (XROWS - rows) * 4; j += 512)
            *(uint4*)(smem + swz((rows + (j >> 2)) * 64 + (j & 3) * 16)) = z4;
    }
    // 5) Convert + scatter-write X (compiler inserts per-chunk vmcnt waits).
#pragma unroll
    for (int i = 0; i < NG; ++i) {
        int idx = t + i * 512;
        if (idx < n4) xwrite4((char*)smem, idx, g[i]);
    }
    __syncthreads();  // the ONLY barrier: publishes X + drains R DMA

    // q-loop: A = R rows (u), B = X rows (positions). Per q: 3 R-frags
    // reused over 4 X-frags -> 7 ds_read_b128 / 12 MFMA (R8 was 5/6).
    f32x4 acc[3][4];
#pragma unroll
    for (int nu = 0; nu < 3; ++nu)
#pragma unroll
        for (int f = 0; f < 4; ++f) acc[nu][f] = (f32x4){0.f, 0.f, 0.f, 0.f};

#pragma unroll
    for (int q = 0; q < KPn; ++q) {
        const int rr = q * Un + lr;
        short8 rf0 = *(const short8*)(smem + BOFF + swz(rr * 64 + ls * 16));
        short8 rf1 = *(const short8*)(smem + BOFF + swz((rr + 16) * 64 + ls * 16));
        short8 rf2 = *(const short8*)(smem + BOFF + swz((rr + 32) * 64 + ls * 16));
#pragma unroll
        for (int f = 0; f < 4; ++f) {
            const int xr = pw + f * 16 + q + lr;
            short8 xf = *(const short8*)(smem + swz(xr * 64 + ls * 16));
            acc[0][f] = __builtin_amdgcn_mfma_f32_16x16x32_bf16(rf0, xf, acc[0][f], 0, 0, 0);
            acc[1][f] = __builtin_amdgcn_mfma_f32_16x16x32_bf16(rf1, xf, acc[1][f], 0, 0, 0);
            acc[2][f] = __builtin_amdgcn_mfma_f32_16x16x32_bf16(rf2, xf, acc[2][f], 0, 0, 0);
        }
    }

    // NT Z stores + per-lane max. Lane owns Z[p=base+pw+f*16+lr][u=nu*16+ls*4..].
    float smax[3][4];
#pragma unroll
    for (int nu = 0; nu < 3; ++nu)
#pragma unroll
        for (int r = 0; r < 4; ++r) smax[nu][r] = -INFINITY;

    float* Zb = Z + (size_t)b * PPn * Un;
#pragma unroll
    for (int f = 0; f < 4; ++f) {
        int p = base_p + pw + f * 16 + lr;
        if (p < PPn) {
            float* zp = Zb + (size_t)p * Un + ls * 4;
#pragma unroll
            for (int nu = 0; nu < 3; ++nu) {
                __builtin_nontemporal_store(acc[nu][f], (f32x4*)(zp + nu * 16));
#pragma unroll
                for (int r = 0; r < 4; ++r)
                    smax[nu][r] = fmaxf(smax[nu][r], acc[nu][f][r]);
            }
        }
    }

    // Per-wave S reduction over the 16 position-lanes, then direct atomics.
    const int grp = b / D2n;
#pragma unroll
    for (int nu = 0; nu < 3; ++nu)
#pragma unroll
        for (int r = 0; r < 4; ++r) {
            float v = smax[nu][r];
            v = fmaxf(v, __shfl_xor(v, 1));
            v = fmaxf(v, __shfl_xor(v, 2));
            v = fmaxf(v, __shfl_xor(v, 4));
            v = fmaxf(v, __shfl_xor(v, 8));
            if (lr == 0)
                atomicMax(&Skey[grp * Un + nu * 16 + ls * 4 + r], fkey(v));
        }
}

// Kernel 3: decode monotone keys -> float S, in place.
__global__ void k_decode(unsigned int* __restrict__ Skey) {
    int t = blockIdx.x * blockDim.x + threadIdx.x;
    if (t < S_SIZE) {
        float f = funkey(Skey[t]);
        ((float*)Skey)[t] = f;
    }
}

extern "C" void kernel_launch(void* const* d_in, const int* in_sizes, int n_in,
                              void* d_out, int out_size, void* d_ws, size_t ws_size,
                              hipStream_t stream) {
    const float* X = (const float*)d_in[0];
    const float* P_logit = (const float*)d_in[1];
    const float* Q = (const float*)d_in[2];

    float* S = (float*)d_out;
    float* Rout = S + S_SIZE;
    float* Z = Rout + R_SIZE;
    unsigned short* Rb = (unsigned short*)d_ws;  // 24576 bytes of ws

    k_profile<<<(S_SIZE + 63) / 64, 64, 0, stream>>>(P_logit, Q, Rout, Rb,
                                                     (unsigned int*)d_out);

    dim3 grid(NBX, Bn);  // 4 x 512 positions = 2048 >= 1993
    k_conv<<<grid, 512, 0, stream>>>(X, Rb, Z, (unsigned int*)d_out);

    k_decode<<<(S_SIZE + 255) / 256, 256, 0, stream>>>((unsigned int*)d_out);
}